// Round 1
// baseline (239.512 us; speedup 1.0000x reference)
//
#include <hip/hip_runtime.h>
#include <math.h>

#define WIN 16
#define KMAX (2 * WIN + 1)

// Kernel 1: per-batch inclusive cumsum of durations (double precision scan),
// centers c[b,n] = cumsum(dur)[b,n] - 0.5*dur[b,n]
__global__ void centers_kernel(const float* __restrict__ dur,
                               float* __restrict__ c, int N) {
    extern __shared__ double s[];
    int b = blockIdx.x;
    int n = threadIdx.x;
    float d = (n < N) ? dur[(size_t)b * N + n] : 0.0f;
    if (n < N) s[n] = (double)d;
    __syncthreads();
    for (int off = 1; off < N; off <<= 1) {
        double v = (n >= off && n < N) ? s[n - off] : 0.0;
        __syncthreads();
        if (n < N) s[n] += v;
        __syncthreads();
    }
    if (n < N) c[(size_t)b * N + n] = (float)(s[n] - 0.5 * (double)d);
}

// Kernel 2: one block per (b,t). Windowed softmax over the <=33 phonemes
// nearest t (numerically identical to the full softmax; Gaussian var=1,
// center spacing ~8), then weighted sum of input rows.
__global__ __launch_bounds__(256) void upsample_kernel(
    const float* __restrict__ x,    // [B,N,H]
    const int* __restrict__ lens,   // [B]
    const float* __restrict__ c,    // [B,N]
    float* __restrict__ out,        // [B,T,H]
    int B, int N, int H, int T) {
    // XCD-bijective swizzle: contiguous t-ranges per XCD for L2 locality.
    int nwg = gridDim.x;
    int bid = blockIdx.x;
    if ((nwg & 7) == 0) {
        int cpx = nwg >> 3;
        bid = (bid & 7) * cpx + (bid >> 3);
    }
    int b = bid / T;
    int t = bid - b * T;

    __shared__ float w_s[KMAX];
    __shared__ int nK_s[2];

    const float* cb = c + (size_t)b * N;
    int L = lens[b];
    if (L < 1) L = 1;
    if (L > N) L = N;
    float tf = (float)t;

    if (threadIdx.x == 0) {
        // lower_bound: first idx in [0,L) with cb[idx] >= tf
        int lo = 0, hi = L;
        while (lo < hi) {
            int mid = (lo + hi) >> 1;
            if (cb[mid] < tf) lo = mid + 1; else hi = mid;
        }
        int j = lo;
        if (j >= L) j = L - 1;
        if (j > 0 && (tf - cb[j - 1]) < (cb[j] - tf)) j--;
        int n0 = j - WIN; if (n0 < 0) n0 = 0;
        int n1 = j + WIN; if (n1 > L - 1) n1 = L - 1;
        nK_s[0] = n0;
        nK_s[1] = n1 - n0 + 1;
    }
    __syncthreads();
    int n0 = nK_s[0];
    int K  = nK_s[1];

    // wave 0: windowed softmax weights
    if (threadIdx.x < 64) {
        int k = threadIdx.x;
        float sc = -3.0e38f;
        if (k < K) {
            float d = tf - cb[n0 + k];
            sc = -0.5f * d * d;
        }
        float m = sc;
        #pragma unroll
        for (int off = 32; off; off >>= 1) m = fmaxf(m, __shfl_xor(m, off));
        float e = (k < K) ? __expf(sc - m) : 0.0f;
        float sum = e;
        #pragma unroll
        for (int off = 32; off; off >>= 1) sum += __shfl_xor(sum, off);
        if (k < K) w_s[k] = e / sum;
    }
    __syncthreads();

    const float2* rowbase = (const float2*)(x + ((size_t)b * N + n0) * (size_t)H);
    float2* ob = (float2*)(out + ((size_t)b * T + t) * (size_t)H);
    int H2 = H >> 1;
    for (int h2 = threadIdx.x; h2 < H2; h2 += blockDim.x) {
        float2 acc = make_float2(0.0f, 0.0f);
        for (int k = 0; k < K; ++k) {
            float wk = w_s[k];
            float2 v = rowbase[(size_t)k * H2 + h2];
            acc.x = fmaf(wk, v.x, acc.x);
            acc.y = fmaf(wk, v.y, acc.y);
        }
        ob[h2] = acc;
    }
}

extern "C" void kernel_launch(void* const* d_in, const int* in_sizes, int n_in,
                              void* d_out, int out_size, void* d_ws, size_t ws_size,
                              hipStream_t stream) {
    const float* x    = (const float*)d_in[0];  // [B,N,H] f32
    const int*   lens = (const int*)d_in[1];    // [B] int
    const float* dur  = (const float*)d_in[2];  // [B,N] f32
    // d_in[3] = output_max_len scalar (derived from sizes instead)

    int B  = in_sizes[1];
    int BN = in_sizes[2];
    int N  = BN / B;
    int H  = in_sizes[0] / BN;
    int T  = out_size / (B * H);

    float* c = (float*)d_ws;  // B*N floats

    centers_kernel<<<B, N, N * sizeof(double), stream>>>(dur, c, N);
    upsample_kernel<<<B * T, 256, 0, stream>>>(x, lens, c, (float*)d_out,
                                               B, N, H, T);
}

// Round 4
// 239.311 us; speedup vs baseline: 1.0008x; 1.0008x over previous
//
#include <hip/hip_runtime.h>
#include <math.h>

#define WIN 16
#define KMAX (2 * WIN + 1)

// Kernel 1: per-batch inclusive cumsum of durations (double precision scan),
// centers c[b,n] = cumsum(dur)[b,n] - 0.5*dur[b,n]   (verbatim round-1)
__global__ void centers_kernel(const float* __restrict__ dur,
                               float* __restrict__ c, int N) {
    extern __shared__ double s[];
    int b = blockIdx.x;
    int n = threadIdx.x;
    float d = (n < N) ? dur[(size_t)b * N + n] : 0.0f;
    if (n < N) s[n] = (double)d;
    __syncthreads();
    for (int off = 1; off < N; off <<= 1) {
        double v = (n >= off && n < N) ? s[n - off] : 0.0;
        __syncthreads();
        if (n < N) s[n] += v;
        __syncthreads();
    }
    if (n < N) c[(size_t)b * N + n] = (float)(s[n] - 0.5 * (double)d);
}

// Kernel 2: one block per (b,t) — verbatim round-1 weight computation
// (verified passing), accumulate loop restructured ONLY for memory-level
// parallelism: 8 independent row loads per batch, fma'd in identical k
// order => bit-identical output to round 1.
__global__ __launch_bounds__(256) void upsample_kernel(
    const float* __restrict__ x,    // [B,N,H]
    const int* __restrict__ lens,   // [B]
    const float* __restrict__ c,    // [B,N]
    float* __restrict__ out,        // [B,T,H]
    int B, int N, int H, int T) {
    // XCD-bijective swizzle: contiguous t-ranges per XCD for L2 locality.
    int nwg = gridDim.x;
    int bid = blockIdx.x;
    if ((nwg & 7) == 0) {
        int cpx = nwg >> 3;
        bid = (bid & 7) * cpx + (bid >> 3);
    }
    int b = bid / T;
    int t = bid - b * T;

    __shared__ float w_s[KMAX];
    __shared__ int nK_s[2];

    const float* cb = c + (size_t)b * N;
    int L = lens[b];
    if (L < 1) L = 1;
    if (L > N) L = N;
    float tf = (float)t;

    if (threadIdx.x == 0) {
        // lower_bound: first idx in [0,L) with cb[idx] >= tf
        int lo = 0, hi = L;
        while (lo < hi) {
            int mid = (lo + hi) >> 1;
            if (cb[mid] < tf) lo = mid + 1; else hi = mid;
        }
        int j = lo;
        if (j >= L) j = L - 1;
        if (j > 0 && (tf - cb[j - 1]) < (cb[j] - tf)) j--;
        int n0 = j - WIN; if (n0 < 0) n0 = 0;
        int n1 = j + WIN; if (n1 > L - 1) n1 = L - 1;
        nK_s[0] = n0;
        nK_s[1] = n1 - n0 + 1;
    }
    __syncthreads();
    int n0 = nK_s[0];
    int K  = nK_s[1];

    // wave 0: windowed softmax weights (verbatim round-1)
    if (threadIdx.x < 64) {
        int k = threadIdx.x;
        float sc = -3.0e38f;
        if (k < K) {
            float d = tf - cb[n0 + k];
            sc = -0.5f * d * d;
        }
        float m = sc;
        #pragma unroll
        for (int off = 32; off; off >>= 1) m = fmaxf(m, __shfl_xor(m, off));
        float e = (k < K) ? __expf(sc - m) : 0.0f;
        float sum = e;
        #pragma unroll
        for (int off = 32; off; off >>= 1) sum += __shfl_xor(sum, off);
        if (k < K) w_s[k] = e / sum;
    }
    __syncthreads();

    const float2* rowbase = (const float2*)(x + ((size_t)b * N + n0) * (size_t)H);
    float2* ob = (float2*)(out + ((size_t)b * T + t) * (size_t)H);
    int H2 = H >> 1;
    for (int h2 = threadIdx.x; h2 < H2; h2 += blockDim.x) {
        const float2* rp = rowbase + h2;
        float2 acc = make_float2(0.0f, 0.0f);
        int k = 0;
        // 8 independent loads in flight, fma'd in ascending-k order
        for (; k + 8 <= K; k += 8) {
            float2 v0 = rp[(size_t)(k + 0) * H2];
            float2 v1 = rp[(size_t)(k + 1) * H2];
            float2 v2 = rp[(size_t)(k + 2) * H2];
            float2 v3 = rp[(size_t)(k + 3) * H2];
            float2 v4 = rp[(size_t)(k + 4) * H2];
            float2 v5 = rp[(size_t)(k + 5) * H2];
            float2 v6 = rp[(size_t)(k + 6) * H2];
            float2 v7 = rp[(size_t)(k + 7) * H2];
            float w0 = w_s[k + 0], w1 = w_s[k + 1], w2 = w_s[k + 2], w3 = w_s[k + 3];
            float w4 = w_s[k + 4], w5 = w_s[k + 5], w6 = w_s[k + 6], w7 = w_s[k + 7];
            acc.x = fmaf(w0, v0.x, acc.x); acc.y = fmaf(w0, v0.y, acc.y);
            acc.x = fmaf(w1, v1.x, acc.x); acc.y = fmaf(w1, v1.y, acc.y);
            acc.x = fmaf(w2, v2.x, acc.x); acc.y = fmaf(w2, v2.y, acc.y);
            acc.x = fmaf(w3, v3.x, acc.x); acc.y = fmaf(w3, v3.y, acc.y);
            acc.x = fmaf(w4, v4.x, acc.x); acc.y = fmaf(w4, v4.y, acc.y);
            acc.x = fmaf(w5, v5.x, acc.x); acc.y = fmaf(w5, v5.y, acc.y);
            acc.x = fmaf(w6, v6.x, acc.x); acc.y = fmaf(w6, v6.y, acc.y);
            acc.x = fmaf(w7, v7.x, acc.x); acc.y = fmaf(w7, v7.y, acc.y);
        }
        for (; k < K; ++k) {
            float wk = w_s[k];
            float2 v = rp[(size_t)k * H2];
            acc.x = fmaf(wk, v.x, acc.x);
            acc.y = fmaf(wk, v.y, acc.y);
        }
        ob[h2] = acc;
    }
}

extern "C" void kernel_launch(void* const* d_in, const int* in_sizes, int n_in,
                              void* d_out, int out_size, void* d_ws, size_t ws_size,
                              hipStream_t stream) {
    const float* x    = (const float*)d_in[0];  // [B,N,H] f32
    const int*   lens = (const int*)d_in[1];    // [B] int
    const float* dur  = (const float*)d_in[2];  // [B,N] f32

    int B  = in_sizes[1];
    int BN = in_sizes[2];
    int N  = BN / B;
    int H  = in_sizes[0] / BN;
    int T  = out_size / (B * H);

    float* c = (float*)d_ws;  // B*N floats

    centers_kernel<<<B, N, N * sizeof(double), stream>>>(dur, c, N);
    upsample_kernel<<<B * T, 256, 0, stream>>>(x, lens, c, (float*)d_out,
                                               B, N, H, T);
}

// Round 5
// 88.993 us; speedup vs baseline: 2.6914x; 2.6891x over previous
//
#include <hip/hip_runtime.h>
#include <math.h>

#define WIN 16   // +/- phoneme-index window (round-1 verified)

// Kernel 1: per-batch inclusive cumsum of durations (double precision scan),
// centers c[b,n] = cumsum(dur)[b,n] - 0.5*dur[b,n]   (verbatim round-1)
__global__ void centers_kernel(const float* __restrict__ dur,
                               float* __restrict__ c, int N) {
    extern __shared__ double s[];
    int b = blockIdx.x;
    int n = threadIdx.x;
    float d = (n < N) ? dur[(size_t)b * N + n] : 0.0f;
    if (n < N) s[n] = (double)d;
    __syncthreads();
    for (int off = 1; off < N; off <<= 1) {
        double v = (n >= off && n < N) ? s[n - off] : 0.0;
        __syncthreads();
        if (n < N) s[n] += v;
        __syncthreads();
    }
    if (n < N) c[(size_t)b * N + n] = (float)(s[n] - 0.5 * (double)d);
}

// Kernel 2: 256-thread blocks of 4 INDEPENDENT waves (no __syncthreads).
// Each wave owns 4 consecutive output frames:
//   - ballot-based lower_bound (no dependent-load chain)
//   - per-t softmax verbatim from the verified round-1 kernel (lane k = w_k)
//   - union-window accumulate: 1 row load feeds 4 frames; weights broadcast
//     via a wave-private LDS float4 table. Out-of-window weights are exactly
//     0.0f => fma is an exact no-op => per-t numerics identical to round 1.
__global__ __launch_bounds__(256, 4) void upsample_wave4(
    const float* __restrict__ x,    // [B,N,H]
    const int* __restrict__ lens,   // [B]
    const float* __restrict__ c,    // [B,N]
    float* __restrict__ out,        // [B,T,H]
    int B, int N, int H, int T) {
    __shared__ float tbl[4][64 * 4];   // per-wave weight table (1 KB each)

    int nwg = gridDim.x;
    int bid = blockIdx.x;
    if ((nwg & 7) == 0) {              // XCD-bijective swizzle
        int cpx = nwg >> 3;
        bid = (bid & 7) * cpx + (bid >> 3);
    }
    int wave = threadIdx.x >> 6;
    int lane = threadIdx.x & 63;

    int tilesPerB = T >> 2;            // frames per tile = 4
    int tw = bid * 4 + wave;           // global tile id
    int b  = tw / tilesPerB;
    int t0 = (tw - b * tilesPerB) << 2;

    const float* cb = c + (size_t)b * N;
    int L = lens[b];
    if (L < 1) L = 1;
    if (L > N) L = N;

    float tf0 = (float)(t0 + 0), tf1 = (float)(t0 + 1);
    float tf2 = (float)(t0 + 2), tf3 = (float)(t0 + 3);

    // ---- fused parallel lower_bound for the 4 frames ----
    int lo0 = 0, lo1 = 0, lo2 = 0, lo3 = 0;
    for (int s = 0; s < N; s += 64) {
        int n = s + lane;
        float v = (n < N) ? cb[n] : 3.0e38f;
        bool inb = (n < L);
        lo0 += __popcll(__ballot(inb && (v < tf0)));
        lo1 += __popcll(__ballot(inb && (v < tf1)));
        lo2 += __popcll(__ballot(inb && (v < tf2)));
        lo3 += __popcll(__ballot(inb && (v < tf3)));
    }

    // ---- per-t window + softmax (round-1 numerics; lane k holds w_k) ----
    auto softmax_t = [&](float tf, int lo, int& a_r, int& e_r, float& w_r) {
        int j = lo;
        if (j >= L) j = L - 1;
        float cj   = cb[j];
        float cjm1 = cb[(j > 0) ? (j - 1) : 0];
        if (j > 0 && (tf - cjm1) < (cj - tf)) j--;
        int a = j - WIN; if (a < 0) a = 0;
        int e = j + WIN; if (e > L - 1) e = L - 1;
        int K = e - a + 1;
        float sc = -3.0e38f;
        if (lane < K) {
            float d = tf - cb[a + lane];
            sc = -0.5f * d * d;
        }
        float m = sc;
        #pragma unroll
        for (int off = 32; off; off >>= 1) m = fmaxf(m, __shfl_xor(m, off));
        float ev = (lane < K) ? __expf(sc - m) : 0.0f;
        float sum = ev;
        #pragma unroll
        for (int off = 32; off; off >>= 1) sum += __shfl_xor(sum, off);
        a_r = a; e_r = e;
        w_r = ev / sum;                 // lanes >= K get exactly 0.0f
    };

    int a0, e0, a1, e1, a2, e2, a3, e3;
    float w0, w1, w2, w3;
    softmax_t(tf0, lo0, a0, e0, w0);
    softmax_t(tf1, lo1, a1, e1, w1);
    softmax_t(tf2, lo2, a2, e2, w2);
    softmax_t(tf3, lo3, a3, e3, w3);

    // ---- union-window accumulate (j monotone => union = [a0, e3]) ----
    int n0 = a0;
    int span = e3 - n0 + 1;
    float* tw_ = tbl[wave];
    const float2* rowbase = (const float2*)(x + ((size_t)b * N + n0) * (size_t)H);
    int H2 = H >> 1;                    // 256 (H = 512)

    float2 acc[4][4];
    #pragma unroll
    for (int i = 0; i < 4; ++i)
        #pragma unroll
        for (int cc = 0; cc < 4; ++cc)
            acc[i][cc] = make_float2(0.0f, 0.0f);

    for (int kb = 0; kb < span; kb += 64) {
        int klen = span - kb; if (klen > 64) klen = 64;

        // build weight float4 for union index n0+kb+lane (masked shfl gather)
        int nn = kb + lane;             // index relative to n0
        unsigned s0 = (unsigned)(nn + n0 - a0);
        unsigned s1 = (unsigned)(nn + n0 - a1);
        unsigned s2 = (unsigned)(nn + n0 - a2);
        unsigned s3 = (unsigned)(nn + n0 - a3);
        float g0 = __shfl(w0, (int)(s0 & 63u));
        float g1 = __shfl(w1, (int)(s1 & 63u));
        float g2 = __shfl(w2, (int)(s2 & 63u));
        float g3 = __shfl(w3, (int)(s3 & 63u));
        float wv0 = (s0 < 64u) ? g0 : 0.0f;
        float wv1 = (s1 < 64u) ? g1 : 0.0f;
        float wv2 = (s2 < 64u) ? g2 : 0.0f;
        float wv3 = (s3 < 64u) ? g3 : 0.0f;
        ((float4*)tw_)[lane] = make_float4(wv0, wv1, wv2, wv3);
        // same-wave LDS ops are issue-ordered; compiler inserts lgkmcnt waits.

        #pragma unroll 2
        for (int k = 0; k < klen; ++k) {
            float4 w4 = ((const float4*)tw_)[k];           // broadcast read
            const float2* row = rowbase + (size_t)(kb + k) * H2;
            #pragma unroll
            for (int cc = 0; cc < 4; ++cc) {
                float2 v = row[cc * 64 + lane];
                acc[0][cc].x = fmaf(w4.x, v.x, acc[0][cc].x);
                acc[0][cc].y = fmaf(w4.x, v.y, acc[0][cc].y);
                acc[1][cc].x = fmaf(w4.y, v.x, acc[1][cc].x);
                acc[1][cc].y = fmaf(w4.y, v.y, acc[1][cc].y);
                acc[2][cc].x = fmaf(w4.z, v.x, acc[2][cc].x);
                acc[2][cc].y = fmaf(w4.z, v.y, acc[2][cc].y);
                acc[3][cc].x = fmaf(w4.w, v.x, acc[3][cc].x);
                acc[3][cc].y = fmaf(w4.w, v.y, acc[3][cc].y);
            }
        }
    }

    // ---- store 4 frames ----
    float2* ob = (float2*)(out + ((size_t)b * T + t0) * (size_t)H);
    #pragma unroll
    for (int i = 0; i < 4; ++i)
        #pragma unroll
        for (int cc = 0; cc < 4; ++cc)
            ob[(size_t)i * H2 + cc * 64 + lane] = acc[i][cc];
}

extern "C" void kernel_launch(void* const* d_in, const int* in_sizes, int n_in,
                              void* d_out, int out_size, void* d_ws, size_t ws_size,
                              hipStream_t stream) {
    const float* x    = (const float*)d_in[0];  // [B,N,H] f32
    const int*   lens = (const int*)d_in[1];    // [B] int
    const float* dur  = (const float*)d_in[2];  // [B,N] f32

    int B  = in_sizes[1];
    int BN = in_sizes[2];
    int N  = BN / B;
    int H  = in_sizes[0] / BN;
    int T  = out_size / (B * H);

    float* c = (float*)d_ws;  // B*N floats

    centers_kernel<<<B, N, N * sizeof(double), stream>>>(dur, c, N);

    int tiles = (B * T) >> 2;           // 4 frames per wave
    int blocks = tiles >> 2;            // 4 waves per block
    upsample_wave4<<<blocks, 256, 0, stream>>>(x, lens, c, (float*)d_out,
                                               B, N, H, T);
}

// Round 6
// 64.759 us; speedup vs baseline: 3.6985x; 1.3742x over previous
//
#include <hip/hip_runtime.h>
#include <math.h>

#define WIN 16   // +/- phoneme-index window (round-1/5 verified)
#define FPB 16   // frames per block (4 waves x 4 frames)
#define CH  16   // staged rows per chunk (32 KB)

// Kernel 1: per-batch inclusive cumsum of durations (double precision scan),
// centers c[b,n] = cumsum(dur)[b,n] - 0.5*dur[b,n]   (verbatim)
__global__ void centers_kernel(const float* __restrict__ dur,
                               float* __restrict__ c, int N) {
    extern __shared__ double s[];
    int b = blockIdx.x;
    int n = threadIdx.x;
    float d = (n < N) ? dur[(size_t)b * N + n] : 0.0f;
    if (n < N) s[n] = (double)d;
    __syncthreads();
    for (int off = 1; off < N; off <<= 1) {
        double v = (n >= off && n < N) ? s[n - off] : 0.0;
        __syncthreads();
        if (n < N) s[n] += v;
        __syncthreads();
    }
    if (n < N) c[(size_t)b * N + n] = (float)(s[n] - 0.5 * (double)d);
}

// Kernel 2: block = 4 waves = 16 consecutive frames. Per-wave search/softmax
// verbatim from the verified round-5 kernel (4 frames/wave). Block-level
// union window staged into LDS in 16-row chunks (burst loads -> ds_write),
// fma loop runs from LDS in identical ascending-k order with identical
// weights (out-of-window = exact 0.0f) => bit-identical to round 5.
__global__ __launch_bounds__(256) void upsample_staged(
    const float* __restrict__ x,    // [B,N,H]
    const int* __restrict__ lens,   // [B]
    const float* __restrict__ c,    // [B,N]
    float* __restrict__ out,        // [B,T,H]
    int B, int N, int H, int T) {
    __shared__ float rows[CH][512];   // 32 KB staged input rows (H = 512)
    __shared__ float tbl[4][CH * 4];  // per-wave weight table (float4 per k)
    __shared__ int   bnd[2];          // block union window [n0, nEnd]

    int nwg = gridDim.x;
    int bid = blockIdx.x;
    if ((nwg & 7) == 0) {             // XCD-bijective swizzle
        int cpx = nwg >> 3;
        bid = (bid & 7) * cpx + (bid >> 3);
    }
    int wave = threadIdx.x >> 6;
    int lane = threadIdx.x & 63;

    int tilesPerB = T / FPB;
    int b   = bid / tilesPerB;
    int t0b = (bid - b * tilesPerB) * FPB;
    int t0  = t0b + wave * 4;         // this wave's first frame

    const float* cb = c + (size_t)b * N;
    int L = lens[b];
    if (L < 1) L = 1;
    if (L > N) L = N;

    float tf0 = (float)(t0 + 0), tf1 = (float)(t0 + 1);
    float tf2 = (float)(t0 + 2), tf3 = (float)(t0 + 3);

    // ---- fused ballot lower_bound for the wave's 4 frames ----
    int lo0 = 0, lo1 = 0, lo2 = 0, lo3 = 0;
    for (int s = 0; s < N; s += 64) {
        int n = s + lane;
        float v = (n < N) ? cb[n] : 3.0e38f;
        bool inb = (n < L);
        lo0 += __popcll(__ballot(inb && (v < tf0)));
        lo1 += __popcll(__ballot(inb && (v < tf1)));
        lo2 += __popcll(__ballot(inb && (v < tf2)));
        lo3 += __popcll(__ballot(inb && (v < tf3)));
    }

    // ---- per-t window + softmax (verbatim round-5; lane k holds w_k) ----
    auto softmax_t = [&](float tf, int lo, int& a_r, int& e_r, float& w_r) {
        int j = lo;
        if (j >= L) j = L - 1;
        float cj   = cb[j];
        float cjm1 = cb[(j > 0) ? (j - 1) : 0];
        if (j > 0 && (tf - cjm1) < (cj - tf)) j--;
        int a = j - WIN; if (a < 0) a = 0;
        int e = j + WIN; if (e > L - 1) e = L - 1;
        int K = e - a + 1;
        float sc = -3.0e38f;
        if (lane < K) {
            float d = tf - cb[a + lane];
            sc = -0.5f * d * d;
        }
        float m = sc;
        #pragma unroll
        for (int off = 32; off; off >>= 1) m = fmaxf(m, __shfl_xor(m, off));
        float ev = (lane < K) ? __expf(sc - m) : 0.0f;
        float sum = ev;
        #pragma unroll
        for (int off = 32; off; off >>= 1) sum += __shfl_xor(sum, off);
        a_r = a; e_r = e;
        w_r = ev / sum;               // lanes >= K get exactly 0.0f
    };

    int a0, e0, a1, e1, a2, e2, a3, e3;
    float w0, w1, w2, w3;
    softmax_t(tf0, lo0, a0, e0, w0);
    softmax_t(tf1, lo1, a1, e1, w1);
    softmax_t(tf2, lo2, a2, e2, w2);
    softmax_t(tf3, lo3, a3, e3, w3);

    // block union window: j monotone in t => [wave0.a0, wave3.e3]
    if (wave == 0 && lane == 0) bnd[0] = a0;
    if (wave == 3 && lane == 0) bnd[1] = e3;
    __syncthreads();
    int n0   = bnd[0];
    int span = bnd[1] - n0 + 1;

    const float* gbase = x + ((size_t)b * N + n0) * (size_t)H;

    float4 acc[4][2];
    #pragma unroll
    for (int i = 0; i < 4; ++i) {
        acc[i][0] = make_float4(0.f, 0.f, 0.f, 0.f);
        acc[i][1] = make_float4(0.f, 0.f, 0.f, 0.f);
    }

    for (int kb = 0; kb < span; kb += CH) {
        int klen = span - kb; if (klen > CH) klen = CH;

        // ---- cooperative stage: wave handles rows {wave, wave+4, ...} ----
        int r0 = wave, r1 = wave + 4, r2 = wave + 8, r3 = wave + 12;
        float4 s0a, s0b, s1a, s1b, s2a, s2b, s3a, s3b;
        if (r0 < klen) { const float4* p = (const float4*)(gbase + (size_t)(kb + r0) * H); s0a = p[lane]; s0b = p[64 + lane]; }
        if (r1 < klen) { const float4* p = (const float4*)(gbase + (size_t)(kb + r1) * H); s1a = p[lane]; s1b = p[64 + lane]; }
        if (r2 < klen) { const float4* p = (const float4*)(gbase + (size_t)(kb + r2) * H); s2a = p[lane]; s2b = p[64 + lane]; }
        if (r3 < klen) { const float4* p = (const float4*)(gbase + (size_t)(kb + r3) * H); s3a = p[lane]; s3b = p[64 + lane]; }
        if (r0 < klen) { float4* d = (float4*)rows[r0]; d[lane] = s0a; d[64 + lane] = s0b; }
        if (r1 < klen) { float4* d = (float4*)rows[r1]; d[lane] = s1a; d[64 + lane] = s1b; }
        if (r2 < klen) { float4* d = (float4*)rows[r2]; d[lane] = s2a; d[64 + lane] = s2b; }
        if (r3 < klen) { float4* d = (float4*)rows[r3]; d[lane] = s3a; d[64 + lane] = s3b; }
        __syncthreads();

        // ---- per-wave weight table for this chunk (masked shfl gather) ----
        int nn = kb + lane;           // union-relative index of this lane's entry
        unsigned q0 = (unsigned)(nn + n0 - a0);
        unsigned q1 = (unsigned)(nn + n0 - a1);
        unsigned q2 = (unsigned)(nn + n0 - a2);
        unsigned q3 = (unsigned)(nn + n0 - a3);
        float g0 = __shfl(w0, (int)(q0 & 63u));
        float g1 = __shfl(w1, (int)(q1 & 63u));
        float g2 = __shfl(w2, (int)(q2 & 63u));
        float g3 = __shfl(w3, (int)(q3 & 63u));
        float wv0 = (q0 < 64u) ? g0 : 0.0f;
        float wv1 = (q1 < 64u) ? g1 : 0.0f;
        float wv2 = (q2 < 64u) ? g2 : 0.0f;
        float wv3 = (q3 < 64u) ? g3 : 0.0f;
        if (lane < klen)
            ((float4*)tbl[wave])[lane] = make_float4(wv0, wv1, wv2, wv3);
        // same-wave LDS write->read: issue-ordered, no barrier needed

        // ---- fma from LDS, ascending k (bit-identical accumulation) ----
        for (int k = 0; k < klen; ++k) {
            float4 w4 = ((const float4*)tbl[wave])[k];     // broadcast
            const float4* row = (const float4*)rows[k];
            float4 va = row[lane];
            float4 vb = row[64 + lane];
            acc[0][0].x = fmaf(w4.x, va.x, acc[0][0].x);
            acc[0][0].y = fmaf(w4.x, va.y, acc[0][0].y);
            acc[0][0].z = fmaf(w4.x, va.z, acc[0][0].z);
            acc[0][0].w = fmaf(w4.x, va.w, acc[0][0].w);
            acc[0][1].x = fmaf(w4.x, vb.x, acc[0][1].x);
            acc[0][1].y = fmaf(w4.x, vb.y, acc[0][1].y);
            acc[0][1].z = fmaf(w4.x, vb.z, acc[0][1].z);
            acc[0][1].w = fmaf(w4.x, vb.w, acc[0][1].w);
            acc[1][0].x = fmaf(w4.y, va.x, acc[1][0].x);
            acc[1][0].y = fmaf(w4.y, va.y, acc[1][0].y);
            acc[1][0].z = fmaf(w4.y, va.z, acc[1][0].z);
            acc[1][0].w = fmaf(w4.y, va.w, acc[1][0].w);
            acc[1][1].x = fmaf(w4.y, vb.x, acc[1][1].x);
            acc[1][1].y = fmaf(w4.y, vb.y, acc[1][1].y);
            acc[1][1].z = fmaf(w4.y, vb.z, acc[1][1].z);
            acc[1][1].w = fmaf(w4.y, vb.w, acc[1][1].w);
            acc[2][0].x = fmaf(w4.z, va.x, acc[2][0].x);
            acc[2][0].y = fmaf(w4.z, va.y, acc[2][0].y);
            acc[2][0].z = fmaf(w4.z, va.z, acc[2][0].z);
            acc[2][0].w = fmaf(w4.z, va.w, acc[2][0].w);
            acc[2][1].x = fmaf(w4.z, vb.x, acc[2][1].x);
            acc[2][1].y = fmaf(w4.z, vb.y, acc[2][1].y);
            acc[2][1].z = fmaf(w4.z, vb.z, acc[2][1].z);
            acc[2][1].w = fmaf(w4.z, vb.w, acc[2][1].w);
            acc[3][0].x = fmaf(w4.w, va.x, acc[3][0].x);
            acc[3][0].y = fmaf(w4.w, va.y, acc[3][0].y);
            acc[3][0].z = fmaf(w4.w, va.z, acc[3][0].z);
            acc[3][0].w = fmaf(w4.w, va.w, acc[3][0].w);
            acc[3][1].x = fmaf(w4.w, vb.x, acc[3][1].x);
            acc[3][1].y = fmaf(w4.w, vb.y, acc[3][1].y);
            acc[3][1].z = fmaf(w4.w, vb.z, acc[3][1].z);
            acc[3][1].w = fmaf(w4.w, vb.w, acc[3][1].w);
        }
        __syncthreads();   // protect rows[] before next chunk overwrite
    }

    // ---- store the wave's 4 frames ----
    float* obase = out + ((size_t)b * T + t0) * (size_t)H;
    #pragma unroll
    for (int i = 0; i < 4; ++i) {
        float4* o = (float4*)(obase + (size_t)i * H);
        o[lane]      = acc[i][0];
        o[64 + lane] = acc[i][1];
    }
}

extern "C" void kernel_launch(void* const* d_in, const int* in_sizes, int n_in,
                              void* d_out, int out_size, void* d_ws, size_t ws_size,
                              hipStream_t stream) {
    const float* x    = (const float*)d_in[0];  // [B,N,H] f32
    const int*   lens = (const int*)d_in[1];    // [B] int
    const float* dur  = (const float*)d_in[2];  // [B,N] f32

    int B  = in_sizes[1];
    int BN = in_sizes[2];
    int N  = BN / B;
    int H  = in_sizes[0] / BN;
    int T  = out_size / (B * H);

    float* c = (float*)d_ws;  // B*N floats

    centers_kernel<<<B, N, N * sizeof(double), stream>>>(dur, c, N);

    int blocks = (B * T) / FPB;         // 16 frames per block
    upsample_staged<<<blocks, 256, 0, stream>>>(x, lens, c, (float*)d_out,
                                                B, N, H, T);
}

// Round 8
// 59.889 us; speedup vs baseline: 3.9993x; 1.0813x over previous
//
#include <hip/hip_runtime.h>
#include <math.h>

#define WIN 16   // +/- phoneme-index window (round-1/5/6 verified)
#define FPW 8    // frames per wave
#define NW  4    // waves per block
#define FPB (FPW * NW)   // 32 frames per block
#define CH  16   // staged rows per chunk (32 KB)

// Kernel 1: per-batch inclusive cumsum of durations (double precision scan),
// centers c[b,n] = cumsum(dur)[b,n] - 0.5*dur[b,n]   (verbatim)
__global__ void centers_kernel(const float* __restrict__ dur,
                               float* __restrict__ c, int N) {
    extern __shared__ double s[];
    int b = blockIdx.x;
    int n = threadIdx.x;
    float d = (n < N) ? dur[(size_t)b * N + n] : 0.0f;
    if (n < N) s[n] = (double)d;
    __syncthreads();
    for (int off = 1; off < N; off <<= 1) {
        double v = (n >= off && n < N) ? s[n - off] : 0.0;
        __syncthreads();
        if (n < N) s[n] += v;
        __syncthreads();
    }
    if (n < N) c[(size_t)b * N + n] = (float)(s[n] - 0.5 * (double)d);
}

// Kernel 2: block = 4 waves x 8 frames = 32 consecutive frames.
// Per-frame softmax verbatim from the verified round-5/6 kernels. Weight
// gather shfls execute with the FULL wave active (round-6 structure; the
// round-7 failure was a divergent shfl) — only the tbl write is predicated.
// Staging via async global_load_lds (wave-uniform linear LDS dest + lane*16,
// linear reads). One ballot search serves 8 frames.
__global__ __launch_bounds__(256, 4) void upsample_staged8(
    const float* __restrict__ x,    // [B,N,H]
    const int* __restrict__ lens,   // [B]
    const float* __restrict__ c,    // [B,N]
    float* __restrict__ out,        // [B,T,H]
    int B, int N, int H, int T) {
    __shared__ float rows[CH][512];        // 32 KB staged input rows (H=512)
    __shared__ float tbl[NW][CH * FPW];    // per-wave weights: 8 per k (2 KB)
    __shared__ int   bnd[2];               // block union window [n0, nEnd]

    int nwg = gridDim.x;
    int bid = blockIdx.x;
    if ((nwg & 7) == 0) {                  // XCD-bijective swizzle
        int cpx = nwg >> 3;
        bid = (bid & 7) * cpx + (bid >> 3);
    }
    int wave = threadIdx.x >> 6;
    int lane = threadIdx.x & 63;

    int tilesPerB = T / FPB;
    int b   = bid / tilesPerB;
    int t0b = (bid - b * tilesPerB) * FPB;
    int t0  = t0b + wave * FPW;            // this wave's first frame

    const float* cb = c + (size_t)b * N;
    int L = lens[b];
    if (L < 1) L = 1;
    if (L > N) L = N;

    float tf[FPW];
    #pragma unroll
    for (int f = 0; f < FPW; ++f) tf[f] = (float)(t0 + f);

    // ---- one ballot lower_bound pass serves all 8 frames ----
    int lo[FPW];
    #pragma unroll
    for (int f = 0; f < FPW; ++f) lo[f] = 0;
    for (int s = 0; s < N; s += 64) {
        int n = s + lane;
        float v = (n < N) ? cb[n] : 3.0e38f;
        bool inb = (n < L);
        #pragma unroll
        for (int f = 0; f < FPW; ++f)
            lo[f] += __popcll(__ballot(inb && (v < tf[f])));
    }

    // ---- per-frame window + softmax (verbatim numerics; lane k = w_k).
    //      8 independent shuffle chains, fully unrolled => latency overlaps.
    int a[FPW], e[FPW];
    float w[FPW];
    #pragma unroll
    for (int f = 0; f < FPW; ++f) {
        int j = lo[f];
        if (j >= L) j = L - 1;
        float cj   = cb[j];
        float cjm1 = cb[(j > 0) ? (j - 1) : 0];
        if (j > 0 && (tf[f] - cjm1) < (cj - tf[f])) j--;
        int af = j - WIN; if (af < 0) af = 0;
        int ef = j + WIN; if (ef > L - 1) ef = L - 1;
        int K = ef - af + 1;
        float sc = -3.0e38f;
        if (lane < K) {
            float d = tf[f] - cb[af + lane];
            sc = -0.5f * d * d;
        }
        float m = sc;
        #pragma unroll
        for (int off = 32; off; off >>= 1) m = fmaxf(m, __shfl_xor(m, off));
        float ev = (lane < K) ? __expf(sc - m) : 0.0f;
        float sum = ev;
        #pragma unroll
        for (int off = 32; off; off >>= 1) sum += __shfl_xor(sum, off);
        a[f] = af; e[f] = ef;
        w[f] = ev / sum;                   // lanes >= K hold exactly 0.0f
    }

    // block union window: nearest-index monotone in t => [w0.a[0], w3.e[7]]
    if (wave == 0 && lane == 0) bnd[0] = a[0];
    if (wave == NW - 1 && lane == 0) bnd[1] = e[FPW - 1];
    __syncthreads();
    int n0   = bnd[0];
    int span = bnd[1] - n0 + 1;

    const float* gbase = x + ((size_t)b * N + n0) * (size_t)H;

    float4 acc[FPW][2];
    #pragma unroll
    for (int f = 0; f < FPW; ++f) {
        acc[f][0] = make_float4(0.f, 0.f, 0.f, 0.f);
        acc[f][1] = make_float4(0.f, 0.f, 0.f, 0.f);
    }

    for (int kb = 0; kb < span; kb += CH) {
        int klen = span - kb; if (klen > CH) klen = CH;

        // ---- async stage: global -> LDS DMA, zero VGPR round-trip.
        //      Linear dest (wave-uniform base + lane*16) == linear read.
        for (int r = wave; r < klen; r += NW) {
            const char* g = (const char*)(gbase + (size_t)(kb + r) * H);
            __builtin_amdgcn_global_load_lds(
                (const __attribute__((address_space(1))) void*)(g + lane * 16),
                (__attribute__((address_space(3))) void*)&rows[r][0], 16, 0, 0);
            __builtin_amdgcn_global_load_lds(
                (const __attribute__((address_space(1))) void*)(g + 1024 + lane * 16),
                (__attribute__((address_space(3))) void*)&rows[r][256], 16, 0, 0);
        }

        // ---- per-wave weight table (shfls with FULL wave active; only the
        //      write is predicated). w[f] is 0 for lanes >= K_f, so q<64
        //      masking alone reproduces the exact per-frame weights.
        int nn = kb + lane;                // union-relative index
        float wv[FPW];
        #pragma unroll
        for (int f = 0; f < FPW; ++f) {
            unsigned q = (unsigned)(nn + n0 - a[f]);
            float g = __shfl(w[f], (int)(q & 63u));
            wv[f] = (q < 64u) ? g : 0.0f;
        }
        if (lane < klen) {
            float4* tw = (float4*)&tbl[wave][lane * FPW];
            tw[0] = make_float4(wv[0], wv[1], wv[2], wv[3]);
            tw[1] = make_float4(wv[4], wv[5], wv[6], wv[7]);
        }
        __syncthreads();                   // DMA drained (vmcnt) + rows ready

        // ---- fma from LDS, ascending k (bit-identical accumulation) ----
        for (int k = 0; k < klen; ++k) {
            const float4* twk = (const float4*)&tbl[wave][k * FPW];  // broadcast
            float4 wlo = twk[0], whi = twk[1];
            const float4* row = (const float4*)rows[k];
            float4 va = row[lane];
            float4 vb = row[64 + lane];
            const float wk[FPW] = { wlo.x, wlo.y, wlo.z, wlo.w,
                                    whi.x, whi.y, whi.z, whi.w };
            #pragma unroll
            for (int f = 0; f < FPW; ++f) {
                acc[f][0].x = fmaf(wk[f], va.x, acc[f][0].x);
                acc[f][0].y = fmaf(wk[f], va.y, acc[f][0].y);
                acc[f][0].z = fmaf(wk[f], va.z, acc[f][0].z);
                acc[f][0].w = fmaf(wk[f], va.w, acc[f][0].w);
                acc[f][1].x = fmaf(wk[f], vb.x, acc[f][1].x);
                acc[f][1].y = fmaf(wk[f], vb.y, acc[f][1].y);
                acc[f][1].z = fmaf(wk[f], vb.z, acc[f][1].z);
                acc[f][1].w = fmaf(wk[f], vb.w, acc[f][1].w);
            }
        }
        __syncthreads();                   // protect rows[] before overwrite
    }

    // ---- store the wave's 8 frames ----
    float* obase = out + ((size_t)b * T + t0) * (size_t)H;
    #pragma unroll
    for (int f = 0; f < FPW; ++f) {
        float4* o = (float4*)(obase + (size_t)f * H);
        o[lane]      = acc[f][0];
        o[64 + lane] = acc[f][1];
    }
}

extern "C" void kernel_launch(void* const* d_in, const int* in_sizes, int n_in,
                              void* d_out, int out_size, void* d_ws, size_t ws_size,
                              hipStream_t stream) {
    const float* x    = (const float*)d_in[0];  // [B,N,H] f32
    const int*   lens = (const int*)d_in[1];    // [B] int
    const float* dur  = (const float*)d_in[2];  // [B,N] f32

    int B  = in_sizes[1];
    int BN = in_sizes[2];
    int N  = BN / B;
    int H  = in_sizes[0] / BN;
    int T  = out_size / (B * H);

    float* c = (float*)d_ws;  // B*N floats

    centers_kernel<<<B, N, N * sizeof(double), stream>>>(dur, c, N);

    int blocks = (B * T) / FPB;             // 32 frames per block
    upsample_staged8<<<blocks, 256, 0, stream>>>(x, lens, c, (float*)d_out,
                                                 B, N, H, T);
}